// Round 4
// baseline (306.831 us; speedup 1.0000x reference)
//
#include <hip/hip_runtime.h>
#include <stdint.h>

#define N_ 8192
#define D_ 1024
// logit = dot(imn,capn)/T; fp8 operands pre-scaled by 16 -> acc = 256*dot
#define EPILOGUE_SCALE (10.0f / 256.0f)
#define ENC_SCALE 16.0f

typedef float f32x4 __attribute__((ext_vector_type(4)));

// Swizzled fragment layout (both operands), 8 MB each:
//   dword index = s*65536 + tile*128 + fl*2 + h   (s in [0,32), tile in [0,512),
//   fl in [0,64), h in [0,2))
//   holds row = tile*16 + (fl&15), k-dwords [s*8 + (fl>>4)*2 + h]
// A wave's fragment load for (tile, s) is 64 lanes x 8B = 512B contiguous.

// Kernel 1: one 16-row tile per block. Phase 1: norms + diag. Phase 2: convert
// to fp8 via LDS. Phase 3: fully-coalesced uint4 stores in fragment order.
// Blocks 0..15 also zero rowsum/colsum (replaces memset dispatch).
__global__ __launch_bounds__(256) void normalize_k(
    const float* __restrict__ im, const float* __restrict__ cap,
    unsigned int* __restrict__ imn, unsigned int* __restrict__ capn,
    float* __restrict__ diag, float* __restrict__ sums /* rowsum|colsum */) {
  __shared__ unsigned int ldsA[16 * 257];
  __shared__ unsigned int ldsB[16 * 257];
  const int til = blockIdx.x;
  const int t = threadIdx.x;
  if (til < 16) ((float4*)sums)[til * 256 + t] = (float4){0.f, 0.f, 0.f, 0.f};

  const int rloc = t >> 4, j = t & 15;
  const int row = til * 16 + rloc;
  const float4* __restrict__ aR = (const float4*)(im + (size_t)row * D_);
  const float4* __restrict__ bR = (const float4*)(cap + (size_t)row * D_);

  float ssa = 0.f, ssb = 0.f, dt = 0.f;
#pragma unroll
  for (int i = 0; i < 16; ++i) {
    const float4 a = aR[j + 16 * i];
    const float4 b = bR[j + 16 * i];
    ssa += a.x * a.x + a.y * a.y + a.z * a.z + a.w * a.w;
    ssb += b.x * b.x + b.y * b.y + b.z * b.z + b.w * b.w;
    dt  += a.x * b.x + a.y * b.y + a.z * b.z + a.w * b.w;
  }
#pragma unroll
  for (int o = 1; o < 16; o <<= 1) {  // reduce across the 16 lanes of this row
    ssa += __shfl_xor(ssa, o, 64);
    ssb += __shfl_xor(ssb, o, 64);
    dt  += __shfl_xor(dt, o, 64);
  }
  const float ra = rsqrtf(ssa), rb = rsqrtf(ssb);
  if (j == 0) diag[row] = dt * ra * rb * 10.0f;
  const float sa = ra * ENC_SCALE, sb = rb * ENC_SCALE;

  // phase 2: re-read (L1/L2 hot), convert, stage in LDS [row][k-dword]
#pragma unroll
  for (int i = 0; i < 16; ++i) {
    const float4 a = aR[j + 16 * i];
    const float4 b = bR[j + 16 * i];
    int pa = __builtin_amdgcn_cvt_pk_fp8_f32(a.x * sa, a.y * sa, 0, false);
    pa = __builtin_amdgcn_cvt_pk_fp8_f32(a.z * sa, a.w * sa, pa, true);
    int pb = __builtin_amdgcn_cvt_pk_fp8_f32(b.x * sb, b.y * sb, 0, false);
    pb = __builtin_amdgcn_cvt_pk_fp8_f32(b.z * sb, b.w * sb, pb, true);
    ldsA[rloc * 257 + j + 16 * i] = (unsigned int)pa;
    ldsB[rloc * 257 + j + 16 * i] = (unsigned int)pb;
  }
  __syncthreads();

  // phase 3: coalesced fragment-order stores, 4 uint4 chunks per thread
#pragma unroll
  for (int i = 0; i < 4; ++i) {
    const int cid = i * 256 + t;       // 1024 chunks: slab s, 16B chunk c4
    const int s = cid >> 5, c4 = cid & 31;
    uint4 va, vb;
#pragma unroll
    for (int q = 0; q < 4; ++q) {
      const int u = c4 * 4 + q;        // dword within this tile's 128-dword run
      const int fl = u >> 1, h = u & 1;
      const int m15 = fl & 15, kgl = fl >> 4;
      const int p = s * 8 + kgl * 2 + h;
      ((unsigned int*)&va)[q] = ldsA[m15 * 257 + p];
      ((unsigned int*)&vb)[q] = ldsB[m15 * 257 + p];
    }
    const size_t d = (size_t)s * 65536 + (size_t)til * 128 + c4 * 4;
    *(uint4*)(imn + d) = va;
    *(uint4*)(capn + d) = vb;
  }
}

// Kernel 2: no-LDS, no-barrier fp8 GEMM + exp + row/col partial sums.
// 128x128 block tile, 4 waves each a 64x64 quadrant of 4x4 16x16x32 MFMA tiles.
// XCD-aware super-tile swizzle: bid&7 = XCD (round-robin dispatch heuristic);
// each XCD walks 8x8-block super-tiles -> 1MB A-panel + 1MB B-panel resident
// in its private 4MB L2 (~2 super-tiles concurrent <= 4MB).
__global__ __launch_bounds__(256, 4) void gemm_lse_k(
    const unsigned char* __restrict__ A,   // swizzled imn
    const unsigned char* __restrict__ B,   // swizzled capn
    float* __restrict__ rowsum, float* __restrict__ colsum) {
  const int t = threadIdx.x;
  const int w = t >> 6, l = t & 63;

  const int bid = blockIdx.x;
  const int xcd = bid & 7;
  const int sidx = bid >> 3;           // 512 blocks per XCD
  const int stl = sidx >> 6;           // 8 super-tiles per XCD
  const int within = sidx & 63;        // 64 blocks per super-tile
  const int g = xcd * 8 + stl;         // global super-tile id [0,64)
  const int sx = g & 7, sy = g >> 3;
  const int bx = sx * 8 + (within & 7);    // row panel [0,64)
  const int by = sy * 8 + (within >> 3);   // col panel [0,64)

  const int rowBase = bx * 128;
  const int colBase = by * 128;
  const int wq_m = (w >> 1) * 64, wq_n = (w & 1) * 64;

  unsigned voffA[4], voffB[4];
#pragma unroll
  for (int i = 0; i < 4; ++i) {
    voffA[i] = (unsigned)((bx * 8 + (w >> 1) * 4 + i) * 512 + l * 8);
    voffB[i] = (unsigned)((by * 8 + (w & 1) * 4 + i) * 512 + l * 8);
  }

  f32x4 acc[4][4];
#pragma unroll
  for (int i = 0; i < 4; ++i)
#pragma unroll
    for (int j = 0; j < 4; ++j)
      acc[i][j] = (f32x4){0.f, 0.f, 0.f, 0.f};

  long a0[4], b0[4], a1[4], b1[4];
#pragma unroll
  for (int i = 0; i < 4; ++i) {
    a0[i] = *(const long*)(A + voffA[i]);
    b0[i] = *(const long*)(B + voffB[i]);
  }

#pragma unroll
  for (int s = 0; s < 32; s += 2) {
    {  // prefetch s+1
      const char* pA = (const char*)A + (size_t)(s + 1) * 262144;
      const char* pB = (const char*)B + (size_t)(s + 1) * 262144;
#pragma unroll
      for (int i = 0; i < 4; ++i) {
        a1[i] = *(const long*)(pA + voffA[i]);
        b1[i] = *(const long*)(pB + voffB[i]);
      }
    }
#pragma unroll
    for (int mt = 0; mt < 4; ++mt)
#pragma unroll
      for (int nt = 0; nt < 4; ++nt)
        acc[mt][nt] = __builtin_amdgcn_mfma_f32_16x16x32_fp8_fp8(
            a0[mt], b0[nt], acc[mt][nt], 0, 0, 0);
    if (s + 2 < 32) {  // prefetch s+2
      const char* pA = (const char*)A + (size_t)(s + 2) * 262144;
      const char* pB = (const char*)B + (size_t)(s + 2) * 262144;
#pragma unroll
      for (int i = 0; i < 4; ++i) {
        a0[i] = *(const long*)(pA + voffA[i]);
        b0[i] = *(const long*)(pB + voffB[i]);
      }
    }
#pragma unroll
    for (int mt = 0; mt < 4; ++mt)
#pragma unroll
      for (int nt = 0; nt < 4; ++nt)
        acc[mt][nt] = __builtin_amdgcn_mfma_f32_16x16x32_fp8_fp8(
            a1[mt], b1[nt], acc[mt][nt], 0, 0, 0);
  }

  // epilogue: exp (fixed-max LSE; |logit| <= 10, no overflow possible)
#pragma unroll
  for (int mt = 0; mt < 4; ++mt)
#pragma unroll
    for (int nt = 0; nt < 4; ++nt)
#pragma unroll
      for (int r = 0; r < 4; ++r)
        acc[mt][nt][r] = __expf(acc[mt][nt][r] * EPILOGUE_SCALE);

  // C/D layout: col = lane&15, row = (lane>>4)*4 + reg  [measured m89/m91]
#pragma unroll
  for (int mt = 0; mt < 4; ++mt)
#pragma unroll
    for (int r = 0; r < 4; ++r) {
      float v = acc[mt][0][r] + acc[mt][1][r] + acc[mt][2][r] + acc[mt][3][r];
      v += __shfl_xor(v, 1, 64);
      v += __shfl_xor(v, 2, 64);
      v += __shfl_xor(v, 4, 64);
      v += __shfl_xor(v, 8, 64);
      if ((l & 15) == 0)
        atomicAdd(&rowsum[rowBase + wq_m + mt * 16 + (l >> 4) * 4 + r], v);
    }
#pragma unroll
  for (int nt = 0; nt < 4; ++nt) {
    float v = 0.f;
#pragma unroll
    for (int mt = 0; mt < 4; ++mt)
      v += acc[mt][nt][0] + acc[mt][nt][1] + acc[mt][nt][2] + acc[mt][nt][3];
    v += __shfl_xor(v, 16, 64);
    v += __shfl_xor(v, 32, 64);
    if (l < 16)
      atomicAdd(&colsum[colBase + wq_n + nt * 16 + l], v);
  }
}

// Kernel 3: scalar reduce.
__global__ __launch_bounds__(256) void finalize_k(
    const float* __restrict__ rowsum, const float* __restrict__ colsum,
    const float* __restrict__ diag, float* __restrict__ out) {
  const int t = threadIdx.x;
  float lse = 0.f, dg = 0.f;
  for (int i = t; i < N_; i += 256) {
    lse += __logf(rowsum[i]) + __logf(colsum[i]);
    dg += diag[i];
  }
#pragma unroll
  for (int o = 32; o > 0; o >>= 1) {
    lse += __shfl_down(lse, o, 64);
    dg  += __shfl_down(dg, o, 64);
  }
  __shared__ float red[2][4];
  const int w = t >> 6, l = t & 63;
  if (l == 0) { red[0][w] = lse; red[1][w] = dg; }
  __syncthreads();
  if (t == 0) {
    lse = red[0][0] + red[0][1] + red[0][2] + red[0][3];
    dg  = red[1][0] + red[1][1] + red[1][2] + red[1][3];
    out[0] = 0.5f * lse / (float)N_ - dg / (float)N_;
  }
}

extern "C" void kernel_launch(void* const* d_in, const int* in_sizes, int n_in,
                              void* d_out, int out_size, void* d_ws, size_t ws_size,
                              hipStream_t stream) {
  const float* im = (const float*)d_in[0];
  const float* cap = (const float*)d_in[1];
  float* out = (float*)d_out;
  char* ws = (char*)d_ws;
  unsigned char* imn = (unsigned char*)ws;                 // 8 MB fp8 (swizzled)
  unsigned char* capn = imn + (size_t)N_ * D_;             // 8 MB fp8 (swizzled)
  float* rowsum = (float*)(ws + 2 * (size_t)N_ * D_);
  float* colsum = rowsum + N_;
  float* diag = colsum + N_;

  normalize_k<<<512, 256, 0, stream>>>(im, cap, (unsigned int*)imn,
                                       (unsigned int*)capn, diag, rowsum);
  gemm_lse_k<<<4096, 256, 0, stream>>>(imn, capn, rowsum, colsum);
  finalize_k<<<1, 256, 0, stream>>>(rowsum, colsum, diag, out);
}

// Round 5
// 272.790 us; speedup vs baseline: 1.1248x; 1.1248x over previous
//
#include <hip/hip_runtime.h>
#include <stdint.h>

#define N_ 8192
#define D_ 1024
// logit = dot(imn,capn)/T; fp8 operands pre-scaled by 16 -> acc = 256*dot
#define EPILOGUE_SCALE (10.0f / 256.0f)
#define ENC_SCALE 16.0f

typedef float f32x4 __attribute__((ext_vector_type(4)));

// Swizzled fragment layout (both operands), 8 MB each:
//   dword index = s*65536 + tile*128 + fl*2 + h   (s in [0,32), tile in [0,512),
//   fl in [0,64), h in [0,2))
//   holds row = tile*16 + (fl&15), k-dwords [s*8 + (fl>>4)*2 + h]
// A wave's fragment load for (tile, s) is 64 lanes x 8B = 512B contiguous.

// Kernel 1: one 16-row tile per block. Phase 1: norms + diag. Phase 2: convert
// to fp8 via LDS. Phase 3: fully-coalesced uint4 stores in fragment order.
// Blocks 0..15 also zero rowsum/colsum (replaces memset dispatch).
__global__ __launch_bounds__(256) void normalize_k(
    const float* __restrict__ im, const float* __restrict__ cap,
    unsigned int* __restrict__ imn, unsigned int* __restrict__ capn,
    float* __restrict__ diag, float* __restrict__ sums /* rowsum|colsum */) {
  __shared__ unsigned int ldsA[16 * 257];
  __shared__ unsigned int ldsB[16 * 257];
  const int til = blockIdx.x;
  const int t = threadIdx.x;
  if (til < 16) ((float4*)sums)[til * 256 + t] = (float4){0.f, 0.f, 0.f, 0.f};

  const int rloc = t >> 4, j = t & 15;
  const int row = til * 16 + rloc;
  const float4* __restrict__ aR = (const float4*)(im + (size_t)row * D_);
  const float4* __restrict__ bR = (const float4*)(cap + (size_t)row * D_);

  float ssa = 0.f, ssb = 0.f, dt = 0.f;
#pragma unroll
  for (int i = 0; i < 16; ++i) {
    const float4 a = aR[j + 16 * i];
    const float4 b = bR[j + 16 * i];
    ssa += a.x * a.x + a.y * a.y + a.z * a.z + a.w * a.w;
    ssb += b.x * b.x + b.y * b.y + b.z * b.z + b.w * b.w;
    dt  += a.x * b.x + a.y * b.y + a.z * b.z + a.w * b.w;
  }
#pragma unroll
  for (int o = 1; o < 16; o <<= 1) {  // reduce across the 16 lanes of this row
    ssa += __shfl_xor(ssa, o, 64);
    ssb += __shfl_xor(ssb, o, 64);
    dt  += __shfl_xor(dt, o, 64);
  }
  const float ra = rsqrtf(ssa), rb = rsqrtf(ssb);
  if (j == 0) diag[row] = dt * ra * rb * 10.0f;
  const float sa = ra * ENC_SCALE, sb = rb * ENC_SCALE;

  // phase 2: re-read (L1/L2 hot), convert, stage in LDS [row][k-dword]
#pragma unroll
  for (int i = 0; i < 16; ++i) {
    const float4 a = aR[j + 16 * i];
    const float4 b = bR[j + 16 * i];
    int pa = __builtin_amdgcn_cvt_pk_fp8_f32(a.x * sa, a.y * sa, 0, false);
    pa = __builtin_amdgcn_cvt_pk_fp8_f32(a.z * sa, a.w * sa, pa, true);
    int pb = __builtin_amdgcn_cvt_pk_fp8_f32(b.x * sb, b.y * sb, 0, false);
    pb = __builtin_amdgcn_cvt_pk_fp8_f32(b.z * sb, b.w * sb, pb, true);
    ldsA[rloc * 257 + j + 16 * i] = (unsigned int)pa;
    ldsB[rloc * 257 + j + 16 * i] = (unsigned int)pb;
  }
  __syncthreads();

  // phase 3: coalesced fragment-order stores, 4 uint4 chunks per thread
#pragma unroll
  for (int i = 0; i < 4; ++i) {
    const int cid = i * 256 + t;       // 1024 chunks: slab s, 16B chunk c4
    const int s = cid >> 5, c4 = cid & 31;
    uint4 va, vb;
#pragma unroll
    for (int q = 0; q < 4; ++q) {
      const int u = c4 * 4 + q;        // dword within this tile's 128-dword run
      const int fl = u >> 1, h = u & 1;
      const int m15 = fl & 15, kgl = fl >> 4;
      const int p = s * 8 + kgl * 2 + h;
      ((unsigned int*)&va)[q] = ldsA[m15 * 257 + p];
      ((unsigned int*)&vb)[q] = ldsB[m15 * 257 + p];
    }
    const size_t d = (size_t)s * 65536 + (size_t)til * 128 + c4 * 4;
    *(uint4*)(imn + d) = va;
    *(uint4*)(capn + d) = vb;
  }
}

// Kernel 2: no-LDS, no-barrier fp8 GEMM + exp + row/col partial sums.
// 128x128 block tile, 4 waves each a 64x64 quadrant of 4x4 16x16x32 MFMA tiles.
// Natural dim3(64,64) mapping (R3: x = row panel fast; R4's explicit XCD
// swizzle regressed -> dispatch mapping assumption was wrong, don't fight it).
// Depth-4 register pipeline: 3 k-slabs of loads in flight ahead of compute.
__global__ __launch_bounds__(256, 4) void gemm_lse_k(
    const unsigned char* __restrict__ A,   // swizzled imn
    const unsigned char* __restrict__ B,   // swizzled capn
    float* __restrict__ rowsum, float* __restrict__ colsum) {
  const int t = threadIdx.x;
  const int w = t >> 6, l = t & 63;
  const int rowBase = blockIdx.x * 128;
  const int colBase = blockIdx.y * 128;
  const int wq_m = (w >> 1) * 64, wq_n = (w & 1) * 64;

  unsigned voffA[4], voffB[4];
#pragma unroll
  for (int i = 0; i < 4; ++i) {
    voffA[i] = (unsigned)((blockIdx.x * 8 + (w >> 1) * 4 + i) * 512 + l * 8);
    voffB[i] = (unsigned)((blockIdx.y * 8 + (w & 1) * 4 + i) * 512 + l * 8);
  }

  f32x4 acc[4][4];
#pragma unroll
  for (int i = 0; i < 4; ++i)
#pragma unroll
    for (int j = 0; j < 4; ++j)
      acc[i][j] = (f32x4){0.f, 0.f, 0.f, 0.f};

  long a_s[4][4], b_s[4][4];
#pragma unroll
  for (int st = 0; st < 3; ++st) {  // preload stages 0..2 (s = 0,1,2)
    const char* pA = (const char*)A + (size_t)st * 262144;
    const char* pB = (const char*)B + (size_t)st * 262144;
#pragma unroll
    for (int i = 0; i < 4; ++i) {
      a_s[st][i] = *(const long*)(pA + voffA[i]);
      b_s[st][i] = *(const long*)(pB + voffB[i]);
    }
  }

#pragma unroll
  for (int s = 0; s < 32; ++s) {
    const int cur = s & 3;
    if (s + 3 < 32) {  // prefetch slab s+3 into the stage being vacated +1
      const int stg = (s + 3) & 3;
      const char* pA = (const char*)A + (size_t)(s + 3) * 262144;
      const char* pB = (const char*)B + (size_t)(s + 3) * 262144;
#pragma unroll
      for (int i = 0; i < 4; ++i) {
        a_s[stg][i] = *(const long*)(pA + voffA[i]);
        b_s[stg][i] = *(const long*)(pB + voffB[i]);
      }
    }
#pragma unroll
    for (int mt = 0; mt < 4; ++mt)
#pragma unroll
      for (int nt = 0; nt < 4; ++nt)
        acc[mt][nt] = __builtin_amdgcn_mfma_f32_16x16x32_fp8_fp8(
            a_s[cur][mt], b_s[cur][nt], acc[mt][nt], 0, 0, 0);
  }

  // epilogue: exp (fixed-max LSE; |logit| <= 10, no overflow possible)
#pragma unroll
  for (int mt = 0; mt < 4; ++mt)
#pragma unroll
    for (int nt = 0; nt < 4; ++nt)
#pragma unroll
      for (int r = 0; r < 4; ++r)
        acc[mt][nt][r] = __expf(acc[mt][nt][r] * EPILOGUE_SCALE);

  // C/D layout: col = lane&15, row = (lane>>4)*4 + reg  [measured m89/m91]
#pragma unroll
  for (int mt = 0; mt < 4; ++mt)
#pragma unroll
    for (int r = 0; r < 4; ++r) {
      float v = acc[mt][0][r] + acc[mt][1][r] + acc[mt][2][r] + acc[mt][3][r];
      v += __shfl_xor(v, 1, 64);
      v += __shfl_xor(v, 2, 64);
      v += __shfl_xor(v, 4, 64);
      v += __shfl_xor(v, 8, 64);
      if ((l & 15) == 0)
        atomicAdd(&rowsum[rowBase + wq_m + mt * 16 + (l >> 4) * 4 + r], v);
    }
#pragma unroll
  for (int nt = 0; nt < 4; ++nt) {
    float v = 0.f;
#pragma unroll
    for (int mt = 0; mt < 4; ++mt)
      v += acc[mt][nt][0] + acc[mt][nt][1] + acc[mt][nt][2] + acc[mt][nt][3];
    v += __shfl_xor(v, 16, 64);
    v += __shfl_xor(v, 32, 64);
    if (l < 16)
      atomicAdd(&colsum[colBase + wq_n + nt * 16 + l], v);
  }
}

// Kernel 3: scalar reduce.
__global__ __launch_bounds__(256) void finalize_k(
    const float* __restrict__ rowsum, const float* __restrict__ colsum,
    const float* __restrict__ diag, float* __restrict__ out) {
  const int t = threadIdx.x;
  float lse = 0.f, dg = 0.f;
  for (int i = t; i < N_; i += 256) {
    lse += __logf(rowsum[i]) + __logf(colsum[i]);
    dg += diag[i];
  }
#pragma unroll
  for (int o = 32; o > 0; o >>= 1) {
    lse += __shfl_down(lse, o, 64);
    dg  += __shfl_down(dg, o, 64);
  }
  __shared__ float red[2][4];
  const int w = t >> 6, l = t & 63;
  if (l == 0) { red[0][w] = lse; red[1][w] = dg; }
  __syncthreads();
  if (t == 0) {
    lse = red[0][0] + red[0][1] + red[0][2] + red[0][3];
    dg  = red[1][0] + red[1][1] + red[1][2] + red[1][3];
    out[0] = 0.5f * lse / (float)N_ - dg / (float)N_;
  }
}

extern "C" void kernel_launch(void* const* d_in, const int* in_sizes, int n_in,
                              void* d_out, int out_size, void* d_ws, size_t ws_size,
                              hipStream_t stream) {
  const float* im = (const float*)d_in[0];
  const float* cap = (const float*)d_in[1];
  float* out = (float*)d_out;
  char* ws = (char*)d_ws;
  unsigned char* imn = (unsigned char*)ws;                 // 8 MB fp8 (swizzled)
  unsigned char* capn = imn + (size_t)N_ * D_;             // 8 MB fp8 (swizzled)
  float* rowsum = (float*)(ws + 2 * (size_t)N_ * D_);
  float* colsum = rowsum + N_;
  float* diag = colsum + N_;

  normalize_k<<<512, 256, 0, stream>>>(im, cap, (unsigned int*)imn,
                                       (unsigned int*)capn, diag, rowsum);
  gemm_lse_k<<<dim3(64, 64), 256, 0, stream>>>(imn, capn, rowsum, colsum);
  finalize_k<<<1, 256, 0, stream>>>(rowsum, colsum, diag, out);
}